// Round 8
// baseline (174.471 us; speedup 1.0000x reference)
//
#include <hip/hip_runtime.h>
#include <math.h>

// SparseMOELayer: N=65536 tokens, D=128, E=16 experts, top-3 routing.
// Outputs concat: logits[N*D] | importance_loss[1] | comb[N*E]
#define NTOK 65536
#define DD   128
#define NE   16
#define NK   3
#define TPB  64                    // tokens per block
#define NBLK (NTOK / TPB)          // 1024

#define OUT_LOSS ((size_t)NTOK * DD)
#define OUT_COMB ((size_t)NTOK * DD + 1)

typedef __bf16 bf16x8 __attribute__((ext_vector_type(8)));
typedef float  f32x4  __attribute__((ext_vector_type(4)));

__device__ __forceinline__ double softplus_d(double z) {
    return fmax(z, 0.0) + log1p(exp(-fabs(z)));
}

// ---------------------------------------------------------------------------
// K0: pack We[e][d][f] fp32 -> WeTp bf16, FRAGMENT-MAJOR (R7-verified):
//   WeTp[e][nt][s][lane][j] holds We[d = s*32 + (lane>>4)*8 + j][f = nt*16 + (lane&15)]
// so a B-frag load is one fully-coalesced 1KB transaction.
// 64 blocks: (e = blk>>2, k-step s = blk&3). Block 0 zeroes imp_g.
// ---------------------------------------------------------------------------
__global__ __launch_bounds__(256) void k_prep(
    const float* __restrict__ We, __bf16* __restrict__ WeTp,
    float* __restrict__ imp_g)
{
    __shared__ __bf16 S[32][DD + 8];
    const int tid = threadIdx.x;
    const int e  = blockIdx.x >> 2;
    const int qd = blockIdx.x & 3;             // == k-step s
    if (blockIdx.x == 0 && tid < NE) imp_g[tid] = 0.f;
    const size_t base = (size_t)e * DD * DD + (size_t)qd * 32 * DD;
    for (int i = tid; i < 32 * DD; i += 256) { // coalesced read, d-quarter
        int dd = i >> 7, f = i & 127;
        S[dd][f] = (__bf16)We[base + i];
    }
    __syncthreads();
    #pragma unroll
    for (int it = 0; it < 2; it++) {
        int lin  = it * 256 + tid;             // 0..511 vectors
        int nt   = lin >> 6;
        int lane = lin & 63;
        int quad = lane >> 4, l15 = lane & 15;
        int f = nt * 16 + l15;
        bf16x8 vv;
        #pragma unroll
        for (int j = 0; j < 8; j++) vv[j] = S[quad * 8 + j][f];
        *(bf16x8*)(WeTp + (size_t)e * 16384 +
                   ((size_t)(nt * 4 + qd) * 64 + lane) * 8) = vv;   // coalesced
    }
}

// ---------------------------------------------------------------------------
// Load one expert's B fragments (2 n-tiles x 4 k-steps) from packed WeTp.
// ---------------------------------------------------------------------------
__device__ __forceinline__ void loadBp(
    bf16x8 (&dst)[2][4], const __bf16* __restrict__ WeTp,
    int e, int wid, int lane)
{
    const __bf16* b = WeTp + (size_t)e * 16384 + (size_t)lane * 8;
    #pragma unroll
    for (int t2 = 0; t2 < 2; t2++)
        #pragma unroll
        for (int s = 0; s < 4; s++)
            dst[t2][s] = *(const bf16x8*)(b + ((wid * 2 + t2) * 4 + s) * 512);
}

// ---------------------------------------------------------------------------
// K1: FUSED gate + expert — OCCUPANCY DIET vs R7 (R7 lesson: true reg use
// ~188 incl AGPRs + 52.7KB LDS -> 2 blocks/CU; 6 serial phases with 8
// waves/CU left all latency exposed).
//  - registers: no B dbuf (-32), acc immediate-consume per a-tile (-24);
//    expert-loop live set ~156; __launch_bounds__(256,3) caps at 170
//    -> 3 waves/SIMD -> 3 blocks/CU
//  - LDS: two-half write staging (yacc32 16.9K unioned over gate scratch /
//    xsb) -> 35.9 KB total
//  - #pragma unroll 1 on expert loop so compiler can't re-inflate Bf
// MFMA 16x16x32 layouts (m89-verified):
//   A: lane l holds A[m=l&15][k=(l>>4)*8+j]; D: col=l&15, row=(l>>4)*4+reg
// ---------------------------------------------------------------------------
__global__ __launch_bounds__(256, 3) void k_fused(
    const float* __restrict__ x, const float* __restrict__ noise,
    const float* __restrict__ Wg, const float* __restrict__ bg,
    const float* __restrict__ Wn, const float* __restrict__ bn,
    const __bf16* __restrict__ WeTp, const float* __restrict__ be,
    float* __restrict__ out, float* __restrict__ imp_g)
{
    __shared__ union {
        struct { double ga[TPB][NE + 1]; double na[TPB][NE + 1]; } g;  // 17408B
        __bf16 xsb[TPB][DD + 8];                                       // 17408B
        float  yacc32[32][DD + 4];                                     // 16896B
    } u;
    __shared__ union {
        struct { float WgT[NE][DD + 4]; float WnT[NE][DD + 4]; } w;    // 16896B
        struct { float beS[NE][DD]; float combT[NE][TPB + 4]; } p;     // 12544B
    } v;
    __shared__ float tkw[TPB][NK];
    __shared__ int   tke[TPB][NK];
    __shared__ float impS[NE];

    const int tid  = threadIdx.x;
    const int n0   = blockIdx.x * TPB;
    const int lane = tid & 63;
    const int wid  = tid >> 6;             // wave -> cols wid*32..+31
    const int l15  = lane & 15;
    const int quad = lane >> 4;
    const int e16  = tid & 15;             // gate-phase expert id
    const int tl   = tid >> 4;             // gate-phase token lane

    // ---- G1: stage transposed gate weights; zero impS ----
    if (tid < NE) impS[tid] = 0.0f;
    for (int i = tid; i < DD * NE; i += 256) {
        int d = i >> 4, ee = i & 15;
        v.w.WgT[ee][d] = Wg[i];
        v.w.WnT[ee][d] = Wn[i];
    }
    __syncthreads();

    // ---- G2: fp64 dots (8 indep chains); x via 16-lane broadcast float4 ----
    {
        const float4* wgp = (const float4*)&v.w.WgT[e16][0];
        const float4* wnp = (const float4*)&v.w.WnT[e16][0];
        for (int g = 0; g < 4; g++) {
            int t = g * 16 + tl;
            const float4* xp = (const float4*)(x + (size_t)(n0 + t) * DD);
            double g0 = 0, g1 = 0, g2 = 0, g3 = 0;
            double h0 = 0, h1 = 0, h2 = 0, h3 = 0;
            #pragma unroll 4
            for (int q = 0; q < DD / 4; q++) {
                float4 xv = xp[q], wg = wgp[q], wn = wnp[q];
                g0 += (double)xv.x * wg.x; g1 += (double)xv.y * wg.y;
                g2 += (double)xv.z * wg.z; g3 += (double)xv.w * wg.w;
                h0 += (double)xv.x * wn.x; h1 += (double)xv.y * wn.y;
                h2 += (double)xv.z * wn.z; h3 += (double)xv.w * wn.w;
            }
            u.g.ga[t][e16] = (g0 + g1) + (g2 + g3);
            u.g.na[t][e16] = (h0 + h1) + (h2 + h3);
        }
    }
    __syncthreads();

    // ---- G3: gate = ga + bg + noise * softplus(na + bn) ----
    {
        const double bge = (double)bg[e16], bne = (double)bn[e16];
        for (int g = 0; g < 4; g++) {
            int t = g * 16 + tl;
            double nz = (double)noise[(size_t)(n0 + t) * NE + e16];
            u.g.ga[t][e16] = u.g.ga[t][e16] + bge
                           + nz * softplus_d(u.g.na[t][e16] + bne);
        }
    }
    __syncthreads();

    // ---- G4: top-3 + softmax (64 threads) ----
    if (tid < TPB) {
        int t = tid;
        double vk[NK]; int ix[NK];
        unsigned taken = 0;
        for (int k = 0; k < NK; k++) {
            double best = -INFINITY; int bi = 0;
            for (int j = 0; j < NE; j++) {
                if (!((taken >> j) & 1u)) {
                    double gv = u.g.ga[t][j];
                    if (gv > best) { best = gv; bi = j; }  // strict >: low idx tie
                }
            }
            taken |= 1u << bi;
            vk[k] = best; ix[k] = bi;
        }
        double e1 = exp(vk[1] - vk[0]);
        double e2 = exp(vk[2] - vk[0]);
        double inv = 1.0 / (1.0 + e1 + e2);
        tke[t][0] = ix[0]; tke[t][1] = ix[1]; tke[t][2] = ix[2];
        tkw[t][0] = (float)inv;
        tkw[t][1] = (float)(e1 * inv);
        tkw[t][2] = (float)(e2 * inv);
    }
    __syncthreads();   // gate scratch (u.g) dead; v.w dead

    // ---- G5/X1: comb (global + LDS combT), impS, beS, xsb staging ----
    for (int g = 0; g < 4; g++) {
        int t = g * 16 + tl;
        float c = 0.f;
        if (tke[t][0] == e16) c = tkw[t][0];
        if (tke[t][1] == e16) c = tkw[t][1];
        if (tke[t][2] == e16) c = tkw[t][2];
        out[OUT_COMB + (size_t)(n0 + t) * NE + e16] = c;
        v.p.combT[e16][t] = c;
        if (c != 0.f) atomicAdd(&impS[e16], c);
    }
    for (int idx = tid; idx < NE * DD; idx += 256)      // stage be
        v.p.beS[idx >> 7][idx & 127] = be[idx];
    for (int idx = tid; idx < TPB * DD; idx += 256) {   // stage x as bf16
        int t = idx >> 7, d = idx & 127;
        u.xsb[t][d] = (__bf16)x[(size_t)(n0 + t) * DD + d];
    }
    __syncthreads();

    // importance partials -> global (device-scope atomics)
    if (tid < NE) atomicAdd(&imp_g[tid], impS[tid]);

    // ---- X2: hoist A fragments (expert-independent, read LDS once) ----
    bf16x8 Af[4][4];
    #pragma unroll
    for (int a = 0; a < 4; a++)
        #pragma unroll
        for (int s = 0; s < 4; s++)
            Af[a][s] = *(const bf16x8*)&u.xsb[a * 16 + l15][32 * s + quad * 8];
    __syncthreads();   // xsb dead -> u.yacc32 reusable later

    // ---- X3: expert loop. Single-buffer B, acc immediate-consume ----
    f32x4 logits[4][2];
    #pragma unroll
    for (int a = 0; a < 4; a++) {
        logits[a][0] = (f32x4){0.f, 0.f, 0.f, 0.f};
        logits[a][1] = (f32x4){0.f, 0.f, 0.f, 0.f};
    }

    #pragma unroll 1
    for (int e = 0; e < NE; e++) {
        bf16x8 Bf[2][4];
        loadBp(Bf, WeTp, e, wid, lane);
        #pragma unroll
        for (int a = 0; a < 4; a++) {
            f32x4 acc0 = {0.f, 0.f, 0.f, 0.f};
            f32x4 acc1 = {0.f, 0.f, 0.f, 0.f};
            #pragma unroll
            for (int s = 0; s < 4; s++) {
                acc0 = __builtin_amdgcn_mfma_f32_16x16x32_bf16(
                    Af[a][s], Bf[0][s], acc0, 0, 0, 0);
                acc1 = __builtin_amdgcn_mfma_f32_16x16x32_bf16(
                    Af[a][s], Bf[1][s], acc1, 0, 0, 0);
            }
            f32x4 cv = *(const f32x4*)&v.p.combT[e][a * 16 + quad * 4];
            #pragma unroll
            for (int r = 0; r < 4; r++) {
                logits[a][0][r] = fmaf(cv[r], acc0[r], logits[a][0][r]);
                logits[a][1][r] = fmaf(cv[r], acc1[r], logits[a][1][r]);
            }
        }
    }

    // ---- X4: bias epilogue ----
    const int nA = wid * 32, nB = nA + 16;
    #pragma unroll 4
    for (int e = 0; e < NE; e++) {
        float bA = v.p.beS[e][nA + l15];
        float bB = v.p.beS[e][nB + l15];
        #pragma unroll
        for (int a = 0; a < 4; a++) {
            f32x4 cv = *(const f32x4*)&v.p.combT[e][a * 16 + quad * 4];
            #pragma unroll
            for (int r = 0; r < 4; r++) {
                logits[a][0][r] = fmaf(cv[r], bA, logits[a][0][r]);
                logits[a][1][r] = fmaf(cv[r], bB, logits[a][1][r]);
            }
        }
    }

    // ---- X5: two-half LDS staging -> coalesced float4 stores ----
    #pragma unroll
    for (int p = 0; p < 2; p++) {
        __syncthreads();                       // protect previous half / xsb
        #pragma unroll
        for (int a2 = 0; a2 < 2; a2++) {
            int a = p * 2 + a2;
            #pragma unroll
            for (int r = 0; r < 4; r++) {
                int row = a2 * 16 + quad * 4 + r;
                u.yacc32[row][nA + l15] = logits[a][0][r];
                u.yacc32[row][nB + l15] = logits[a][1][r];
            }
        }
        __syncthreads();
        float* op = out + (size_t)(n0 + p * 32) * DD;
        for (int i4 = tid; i4 < 32 * DD / 4; i4 += 256) {
            int t = i4 >> 5, f4 = i4 & 31;
            *(f32x4*)(op + i4 * 4) = *(const f32x4*)&u.yacc32[t][f4 * 4];
        }
    }
}

// ---------------------------------------------------------------------------
// K2: loss from 16 globally-accumulated importances.
// ---------------------------------------------------------------------------
__global__ __launch_bounds__(64) void k_loss(
    const float* __restrict__ imp_g, float* __restrict__ out)
{
    if (threadIdx.x == 0) {
        double mean = 0.0;
        for (int i = 0; i < NE; i++) mean += (double)imp_g[i];
        mean /= NE;
        double var = 0.0;
        for (int i = 0; i < NE; i++) {
            double d = (double)imp_g[i] - mean; var += d * d;
        }
        var /= (NE - 1);                    // ddof=1
        out[OUT_LOSS] = (float)(var / (mean * mean));
    }
}

// ---------------------------------------------------------------------------
extern "C" void kernel_launch(void* const* d_in, const int* in_sizes, int n_in,
                              void* d_out, int out_size, void* d_ws, size_t ws_size,
                              hipStream_t stream)
{
    (void)in_sizes; (void)n_in; (void)out_size; (void)ws_size;
    const float* x     = (const float*)d_in[0];
    const float* noise = (const float*)d_in[1];
    const float* Wg    = (const float*)d_in[2];
    const float* bg    = (const float*)d_in[3];
    const float* Wn    = (const float*)d_in[4];
    const float* bn    = (const float*)d_in[5];
    const float* We    = (const float*)d_in[6];
    const float* be    = (const float*)d_in[7];
    float* out = (float*)d_out;

    char*   ws    = (char*)d_ws;
    float*  imp_g = (float*)ws;                  // 64 B (16 floats)
    __bf16* WeTp  = (__bf16*)(ws + 1024);        // 512 KB, 16B-aligned

    hipLaunchKernelGGL(k_prep, dim3(64), dim3(256), 0, stream,
                       We, WeTp, imp_g);
    hipLaunchKernelGGL(k_fused, dim3(NBLK), dim3(256), 0, stream,
                       x, noise, Wg, bg, Wn, bn, WeTp, be, out, imp_g);
    hipLaunchKernelGGL(k_loss, dim3(1), dim3(64), 0, stream, imp_g, out);
}